// Round 9
// baseline (325.628 us; speedup 1.0000x reference)
//
#include <hip/hip_runtime.h>

using f16 = _Float16;
typedef _Float16 h8 __attribute__((ext_vector_type(8)));
typedef _Float16 h4 __attribute__((ext_vector_type(4)));
typedef float f4 __attribute__((ext_vector_type(4)));
typedef unsigned int u32;
typedef unsigned long long u64;

#define DEVI static __device__ __forceinline__

DEVI f4 mfma16(h8 a, h8 b, f4 c) {
  return __builtin_amdgcn_mfma_f32_16x16x32_f16(a, b, c, 0, 0, 0);
}

// async global->LDS, 16B per lane. lds base must be wave-uniform; HW scatters lane i at base + i*16.
DEVI void gl_lds16(const f16* g, f16* l) {
  __builtin_amdgcn_global_load_lds(
      (const __attribute__((address_space(1))) u32*)g,
      (__attribute__((address_space(3))) u32*)l, 16, 0, 0);
}

DEVI u32 pkh2(float a, float b) {
  union { f16 h[2]; u32 u; } x;
  x.h[0] = (f16)a; x.h[1] = (f16)b;
  return x.u;
}

// ---------------- fp32 -> fp16 convert ----------------
typedef float fv4 __attribute__((ext_vector_type(4)));

__global__ __launch_bounds__(256) void k_cvt(const float* __restrict__ in,
                                             f16* __restrict__ out, int n4) {
  int i = blockIdx.x * 256 + threadIdx.x;
  if (i >= n4) return;
  fv4 v = ((const fv4*)in)[i];
  h4 o;
  o[0] = (f16)v[0]; o[1] = (f16)v[1]; o[2] = (f16)v[2]; o[3] = (f16)v[3];
  ((h4*)out)[i] = o;
}

// ---------------- RoPE cos/sin table ----------------
__global__ __launch_bounds__(256) void k_rope_tbl(float* __restrict__ tbl) {
  int i = blockIdx.x * 256 + threadIdx.x;  // 2048*64
  int t = i >> 6, d = i & 63;
  float invf = exp2f(-(float)d * (13.287712379549449f / 64.f));
  float a = (float)t * invf;
  tbl[2 * i]     = cosf(a);
  tbl[2 * i + 1] = sinf(a);
}

// ---------------- GEMM: m97 structure + proven swizzle ----------------
// C[M][N] = A[M][K] * Bt[N][K]^T + bias. BM=BN=128, BK=64, 4 waves (2x2, wave tile 64x64).
// SINGLE-buffered 32KB LDS; per K-tile: stage -> sync -> 16 ds_read + 32 MFMA -> sync.
// Latency hiding comes from CROSS-BLOCK co-residency (3-4 blocks/CU; m97/m114 mechanism),
// not intra-block pipelining (R5-R8 showed 1-block/CU phase scheduling is pinned ~31%).
// Swizzle (R4-measured 0 conflicts): stage = linear LDS dest + pre-swizzled global source
// chunk (lane&7)^(lane>>3); read chunk = logical ^ (row&7) via ^cq7 (row%8 == colq%8).
// Grids: QKV 1536 blocks (6/CU, exact balance), out-proj 512 (2/CU, exact balance).
template <int F32OUT>
__global__ __launch_bounds__(256) void k_gemm97(const f16* __restrict__ A,
                                                const f16* __restrict__ Bt,
                                                const float* __restrict__ bias,
                                                void* __restrict__ Cp,
                                                int M, int N, int K, int gy) {
  __shared__ f16 sA[128 * 64];
  __shared__ f16 sB[128 * 64];
  const int tid = threadIdx.x;
  const int w = tid >> 6, lane = tid & 63;
  const int g = lane >> 4, colq = lane & 15;
  const int wr = w >> 1, wc = w & 1;

  // bijective XCD swizzle (gridDim.x % 8 == 0), bm-fast within XCD chunk
  const int nwg = gridDim.x;
  const int q8 = nwg >> 3;
  const int swz = (blockIdx.x & 7) * q8 + (blockIdx.x >> 3);
  const int bm = swz % gy, bn = swz / gy;

  const f16* Ab = A + (size_t)bm * 128 * K;
  const f16* Bb = Bt + (size_t)bn * 128 * K;
  const int nt = K >> 6;

  const int srow = lane >> 3;               // 0..7
  const int schunk = (lane & 7) ^ srow;     // pre-swizzled source chunk
  const int cq7 = colq & 7;

  f4 acc[4][4] = {};
  const int rowA0 = wr * 64 + colq;
  const int rowB0 = wc * 64 + colq;

  for (int t = 0; t < nt; ++t) {
    const int k0 = t << 6;
    // ---- stage K-tile t (4+4 gl_lds per thread) ----
#pragma unroll
    for (int j = 0; j < 4; ++j) {
      const int r = (w * 4 + j) * 8;  // 8-row group; lane adds srow
      gl_lds16(Ab + (size_t)(r + srow) * K + k0 + schunk * 8, sA + r * 64);
      gl_lds16(Bb + (size_t)(r + srow) * K + k0 + schunk * 8, sB + r * 64);
    }
    __syncthreads();
    // ---- compute ----
    h8 af[2][4], bf[2][4];
#pragma unroll
    for (int kki = 0; kki < 2; ++kki) {
#pragma unroll
      for (int m = 0; m < 4; ++m)
        af[kki][m] = *(const h8*)(sA + (rowA0 + m * 16) * 64 + (((kki * 4 + g) ^ cq7) * 8));
#pragma unroll
      for (int n = 0; n < 4; ++n)
        bf[kki][n] = *(const h8*)(sB + (rowB0 + n * 16) * 64 + (((kki * 4 + g) ^ cq7) * 8));
    }
#pragma unroll
    for (int m = 0; m < 4; ++m)
#pragma unroll
      for (int n = 0; n < 4; ++n)
#pragma unroll
        for (int kki = 0; kki < 2; ++kki)
          acc[m][n] = mfma16(af[kki][m], bf[kki][n], acc[m][n]);
    __syncthreads();
  }

  // ---- epilogue ----
#pragma unroll
  for (int n = 0; n < 4; ++n) {
    const int col = bn * 128 + wc * 64 + n * 16 + colq;
    const float bv = bias[col];
#pragma unroll
    for (int m = 0; m < 4; ++m) {
      const int row0 = bm * 128 + wr * 64 + m * 16 + 4 * g;
#pragma unroll
      for (int r = 0; r < 4; ++r) {
        float v = acc[m][n][r] + bv;
        if constexpr (F32OUT) {
          ((float*)Cp)[(size_t)(row0 + r) * N + col] = v;
        } else {
          ((f16*)Cp)[(size_t)(row0 + r) * N + col] = (f16)v;
        }
      }
    }
  }
}

// ---------------- fused RoPE + V-transpose: qkv -> Q, K (rope'd), Vt ----------------
__global__ __launch_bounds__(256) void k_ropev(const f16* __restrict__ qkv,
                                               const float* __restrict__ tbl,
                                               f16* __restrict__ Q, f16* __restrict__ K,
                                               f16* __restrict__ Vt) {
  __shared__ f16 ldsT[128 * 40];
  const int bh = blockIdx.y, t0 = blockIdx.x * 32;
  const int b = bh >> 4, h = bh & 15;
  const int tid = threadIdx.x;
  // ---- V load -> LDS transpose ----
#pragma unroll
  for (int cc = 0; cc < 2; ++cc) {
    int task = tid + cc * 256;
    int row = task >> 4;
    int ch = task & 15;
    h8 v = *(const h8*)(qkv + (size_t)(b * 2048 + t0 + row) * 6144 + 4096 + h * 128 + ch * 8);
#pragma unroll
    for (int j = 0; j < 8; ++j) ldsT[(ch * 8 + j) * 40 + row] = v[j];
  }
  // ---- RoPE for Q,K ----
  const float SQ = 0.088388347648318447f * 1.4426950408889634f;
#pragma unroll
  for (int cc = 0; cc < 8; ++cc) {
    int task = tid + cc * 256;       // 0..2047
    int row = task >> 6;             // 0..31
    int d = task & 63;               // pair index
    int t = t0 + row;
    const f16* src = qkv + (size_t)(b * 2048 + t) * 6144 + h * 128 + 2 * d;
    union { u32 u; f16 h2[2]; } qa, ka, qo, ko;
    qa.u = *(const u32*)src;
    ka.u = *(const u32*)(src + 2048);
    float c = tbl[2 * (t * 64 + d)];
    float s = tbl[2 * (t * 64 + d) + 1];
    float q0f = (float)qa.h2[0], q1f = (float)qa.h2[1];
    float k0f = (float)ka.h2[0], k1f = (float)ka.h2[1];
    qo.h2[0] = (f16)((q0f * c - q1f * s) * SQ);
    qo.h2[1] = (f16)((q1f * c + q0f * s) * SQ);
    ko.h2[0] = (f16)(k0f * c - k1f * s);
    ko.h2[1] = (f16)(k1f * c + k0f * s);
    *(u32*)(Q + ((size_t)bh * 2048 + t) * 128 + 2 * d) = qo.u;
    *(u32*)(K + ((size_t)bh * 2048 + t) * 128 + 2 * d) = ko.u;
  }
  __syncthreads();
  // ---- V store transposed ----
  int d = tid >> 1, seg = tid & 1;
  h8 v0 = *(const h8*)(ldsT + d * 40 + seg * 16);
  h8 v1 = *(const h8*)(ldsT + d * 40 + seg * 16 + 8);
  f16* dst = Vt + ((size_t)bh * 128 + d) * 2048 + t0 + seg * 16;
  *(h8*)dst = v0;
  *(h8*)(dst + 8) = v1;
}

// ---------------- causal flash attention, LDS-staged, paired panels ----------------
DEVI void stage_tiles(const f16* __restrict__ Kg, const f16* __restrict__ Vtg,
                      f16* bufK, f16* bufV, int kv, int w, int lane) {
#pragma unroll
  for (int jj = 0; jj < 4; ++jj) {
    const int j = w * 4 + jj;
    const int rK = j * 4 + (lane >> 4);
    const int cK = (lane & 15) ^ ((rK & 7) << 1);
    gl_lds16(Kg + (size_t)(kv + rK) * 128 + cK * 8, bufK + j * 512);
    const int rV = j * 8 + (lane >> 3);
    const int cV = (lane & 7) ^ (rV & 7);
    gl_lds16(Vtg + (size_t)rV * 2048 + kv + cV * 8, bufV + j * 512);
  }
}

__global__ __launch_bounds__(256, 1) void k_attn(const f16* __restrict__ Q,
                                                 const f16* __restrict__ K,
                                                 const f16* __restrict__ Vt,
                                                 f16* __restrict__ O) {
  __shared__ f16 lds[2][16384];  // per buffer: K tile [0,8192), V tile [8192,16384)
  const int tid = threadIdx.x;
  const int w = tid >> 6, lane = tid & 63;
  const int g = lane >> 4, q = lane & 15;
  const int bid = blockIdx.x;
  const int bh = bid & 31;   // head: XCD x serves heads {x, x+8, x+16, x+24}
  const int b = bid >> 5;    // pair index 0..7

  const f16* Kg = K + (size_t)bh * 2048 * 128;
  const f16* Vtg = Vt + (size_t)bh * 128 * 2048;
  const int qx2 = (q & 7) << 1;
  const int qx = q & 7;

  for (int ph = 0; ph < 2; ++ph) {
    const int p = ph ? (15 - b) : b;  // panel 0..15 (128 rows each)
    const int q0w = p * 128 + w * 32;
    const int nit = 2 * (p + 1);

    h8 qf[2][4];
#pragma unroll
    for (int set = 0; set < 2; ++set)
#pragma unroll
      for (int d4 = 0; d4 < 4; ++d4)
        qf[set][d4] = *(const h8*)(Q + ((size_t)bh * 2048 + q0w + 16 * set + q) * 128 + d4 * 32 + g * 8);

    stage_tiles(Kg, Vtg, lds[0], lds[0] + 8192, 0, w, lane);
    asm volatile("s_waitcnt vmcnt(0)" ::: "memory");
    __builtin_amdgcn_s_barrier();

    f4 ot[2][8] = {};
    float mrun[2] = {-3.0e38f, -3.0e38f};
    float lrun[2] = {0.f, 0.f};

    for (int it = 0; it < nit; ++it) {
      const int kv0 = it * 64;
      f16* bufK = lds[it & 1];
      f16* bufV = bufK + 8192;
      if (it + 1 < nit) {
        f16* nb = lds[(it + 1) & 1];
        stage_tiles(Kg, Vtg, nb, nb + 8192, kv0 + 64, w, lane);
      }
      if (kv0 < q0w + 32) {
        f4 st[2][4] = {{{0.f,0.f,0.f,0.f},{0.f,0.f,0.f,0.f},{0.f,0.f,0.f,0.f},{0.f,0.f,0.f,0.f}},
                       {{0.f,0.f,0.f,0.f},{0.f,0.f,0.f,0.f},{0.f,0.f,0.f,0.f},{0.f,0.f,0.f,0.f}}};
#pragma unroll
        for (int d4 = 0; d4 < 4; ++d4) {
          h8 kf[4];
#pragma unroll
          for (int s = 0; s < 4; ++s)
            kf[s] = *(const h8*)(bufK + ((16 * s + q) * 16 + ((4 * d4 + g) ^ qx2)) * 8);
#pragma unroll
          for (int set = 0; set < 2; ++set)
#pragma unroll
            for (int s = 0; s < 4; ++s)
              st[set][s] = mfma16(kf[s], qf[set][d4], st[set][s]);
        }
        if (kv0 + 63 > q0w) {
#pragma unroll
          for (int set = 0; set < 2; ++set) {
            const int qcol = q0w + 16 * set + q;
#pragma unroll
            for (int s = 0; s < 4; ++s)
#pragma unroll
              for (int r = 0; r < 4; ++r)
                if (kv0 + s * 16 + 4 * g + r > qcol) st[set][s][r] = -3.0e38f;
          }
        }
        float pm[2];
#pragma unroll
        for (int set = 0; set < 2; ++set) {
          float m0 = st[set][0][0];
#pragma unroll
          for (int s = 0; s < 4; ++s)
#pragma unroll
            for (int r = 0; r < 4; ++r) m0 = fmaxf(m0, st[set][s][r]);
          m0 = fmaxf(m0, __shfl_xor(m0, 16));
          m0 = fmaxf(m0, __shfl_xor(m0, 32));
          pm[set] = m0;
        }
        const bool ok = (pm[0] <= mrun[0] + 8.0f) && (pm[1] <= mrun[1] + 8.0f);
        if (!__all(ok)) {
#pragma unroll
          for (int set = 0; set < 2; ++set) {
            float mnew = fmaxf(mrun[set], pm[set]);
            float corr = exp2f(mrun[set] - mnew);
            lrun[set] *= corr;
#pragma unroll
            for (int dt = 0; dt < 8; ++dt) ot[set][dt] *= corr;
            mrun[set] = mnew;
          }
        }
#pragma unroll
        for (int set = 0; set < 2; ++set) {
          float ps = 0.f;
#pragma unroll
          for (int s = 0; s < 4; ++s)
#pragma unroll
            for (int r = 0; r < 4; ++r) {
              st[set][s][r] = exp2f(st[set][s][r] - mrun[set]);
              ps += st[set][s][r];
            }
          ps += __shfl_xor(ps, 16);
          ps += __shfl_xor(ps, 32);
          lrun[set] += ps;
        }
        union { u32 u[4]; h8 h; } pb[2][2];
        const int s0l = ((g & 1) << 5) | q;
        const bool hi = g >= 2;
#pragma unroll
        for (int set = 0; set < 2; ++set)
#pragma unroll
          for (int hh = 0; hh < 2; ++hh) {
            u32 wA0 = pkh2(st[set][2 * hh][0], st[set][2 * hh][1]);
            u32 wB0 = pkh2(st[set][2 * hh][2], st[set][2 * hh][3]);
            u32 wA1 = pkh2(st[set][2 * hh + 1][0], st[set][2 * hh + 1][1]);
            u32 wB1 = pkh2(st[set][2 * hh + 1][2], st[set][2 * hh + 1][3]);
            u32 a0 = (u32)__shfl((int)wA0, s0l),      a1 = (u32)__shfl((int)wA1, s0l);
            u32 b0 = (u32)__shfl((int)wB0, s0l),      b1 = (u32)__shfl((int)wB1, s0l);
            u32 c0 = (u32)__shfl((int)wA0, s0l + 16), c1 = (u32)__shfl((int)wA1, s0l + 16);
            u32 d0 = (u32)__shfl((int)wB0, s0l + 16), d1 = (u32)__shfl((int)wB1, s0l + 16);
            pb[set][hh].u[0] = hi ? a1 : a0;
            pb[set][hh].u[1] = hi ? b1 : b0;
            pb[set][hh].u[2] = hi ? c1 : c0;
            pb[set][hh].u[3] = hi ? d1 : d0;
          }
#pragma unroll
        for (int hh = 0; hh < 2; ++hh)
#pragma unroll
          for (int dt = 0; dt < 8; ++dt) {
            h8 vf = *(const h8*)(bufV + ((dt * 16 + q) * 8 + ((4 * hh + g) ^ qx)) * 8);
#pragma unroll
            for (int set = 0; set < 2; ++set)
              ot[set][dt] = mfma16(vf, pb[set][hh].h, ot[set][dt]);
          }
      }
      asm volatile("s_waitcnt vmcnt(0)" ::: "memory");
      __builtin_amdgcn_s_barrier();
    }

#pragma unroll
    for (int set = 0; set < 2; ++set) {
      float linv = 1.0f / lrun[set];
      f16* Ob = O + ((size_t)(bh >> 4) * 2048 + q0w + 16 * set + q) * 2048 + (bh & 15) * 128 + 4 * g;
#pragma unroll
      for (int dt = 0; dt < 8; ++dt) {
        union { f16 hh4[4]; u64 u; } o;
#pragma unroll
        for (int r = 0; r < 4; ++r) o.hh4[r] = (f16)(ot[set][dt][r] * linv);
        *(u64*)(Ob + dt * 16) = o.u;
      }
    }
  }
}

// ---------------- launch ----------------
extern "C" void kernel_launch(void* const* d_in, const int* in_sizes, int n_in,
                              void* d_out, int out_size, void* d_ws, size_t ws_size,
                              hipStream_t stream) {
  (void)in_sizes; (void)n_in; (void)out_size; (void)ws_size;
  const float* x    = (const float*)d_in[0];
  const float* Wqkv = (const float*)d_in[1];
  const float* bqkv = (const float*)d_in[2];
  const float* Wo   = (const float*)d_in[3];
  const float* bo   = (const float*)d_in[4];

  char* ws = (char*)d_ws;
  f16* xb    = (f16*)ws; ws += (size_t)4096 * 2048 * 2;
  f16* wqkvb = (f16*)ws; ws += (size_t)6144 * 2048 * 2;
  f16* wob   = (f16*)ws; ws += (size_t)2048 * 2048 * 2;
  f16* qkvb  = (f16*)ws; ws += (size_t)4096 * 6144 * 2;
  f16* Qb    = (f16*)ws; ws += (size_t)32 * 2048 * 128 * 2;
  f16* Kb    = (f16*)ws; ws += (size_t)32 * 2048 * 128 * 2;
  f16* Vtb   = (f16*)ws; ws += (size_t)32 * 128 * 2048 * 2;
  f16* attb  = (f16*)ws; ws += (size_t)4096 * 2048 * 2;
  float* tbl = (float*)ws; ws += (size_t)2048 * 64 * 2 * 4;

  k_cvt<<<8192, 256, 0, stream>>>(x, xb, 2097152);
  k_cvt<<<12288, 256, 0, stream>>>(Wqkv, wqkvb, 3145728);
  k_cvt<<<4096, 256, 0, stream>>>(Wo, wob, 1048576);
  k_rope_tbl<<<512, 256, 0, stream>>>(tbl);

  // QKV: 128x128 tiles, M=4096 (gy=32), N=6144 (gx=48) -> 1536 blocks (6/CU, balanced)
  k_gemm97<0><<<1536, 256, 0, stream>>>(xb, wqkvb, bqkv, qkvb, 4096, 6144, 2048, 32);

  // fused RoPE + V-transpose
  k_ropev<<<dim3(64, 32), 256, 0, stream>>>(qkvb, tbl, Qb, Kb, Vtb);

  k_attn<<<256, 256, 0, stream>>>(Qb, Kb, Vtb, attb);

  // out-proj: 128x128 tiles, M=4096 (gy=32), N=2048 (gx=16) -> 512 blocks (2/CU, balanced)
  k_gemm97<1><<<512, 256, 0, stream>>>(attb, wob, bo, d_out, 4096, 2048, 2048, 32);
}

// Round 10
// 313.752 us; speedup vs baseline: 1.0379x; 1.0379x over previous
//
#include <hip/hip_runtime.h>

using f16 = _Float16;
typedef _Float16 h8 __attribute__((ext_vector_type(8)));
typedef _Float16 h4 __attribute__((ext_vector_type(4)));
typedef float f4 __attribute__((ext_vector_type(4)));
typedef unsigned int u32;
typedef unsigned long long u64;

#define DEVI static __device__ __forceinline__

DEVI f4 mfma16(h8 a, h8 b, f4 c) {
  return __builtin_amdgcn_mfma_f32_16x16x32_f16(a, b, c, 0, 0, 0);
}

// async global->LDS, 16B per lane. lds base must be wave-uniform; HW scatters lane i at base + i*16.
DEVI void gl_lds16(const f16* g, f16* l) {
  __builtin_amdgcn_global_load_lds(
      (const __attribute__((address_space(1))) u32*)g,
      (__attribute__((address_space(3))) u32*)l, 16, 0, 0);
}

DEVI u32 pkh2(float a, float b) {
  union { f16 h[2]; u32 u; } x;
  x.h[0] = (f16)a; x.h[1] = (f16)b;
  return x.u;
}

// ---------------- fp32 -> fp16 convert ----------------
typedef float fv4 __attribute__((ext_vector_type(4)));

__global__ __launch_bounds__(256) void k_cvt(const float* __restrict__ in,
                                             f16* __restrict__ out, int n4) {
  int i = blockIdx.x * 256 + threadIdx.x;
  if (i >= n4) return;
  fv4 v = ((const fv4*)in)[i];
  h4 o;
  o[0] = (f16)v[0]; o[1] = (f16)v[1]; o[2] = (f16)v[2]; o[3] = (f16)v[3];
  ((h4*)out)[i] = o;
}

// ---------------- RoPE cos/sin table ----------------
__global__ __launch_bounds__(256) void k_rope_tbl(float* __restrict__ tbl) {
  int i = blockIdx.x * 256 + threadIdx.x;  // 2048*64
  int t = i >> 6, d = i & 63;
  float invf = exp2f(-(float)d * (13.287712379549449f / 64.f));
  float a = (float)t * invf;
  tbl[2 * i]     = cosf(a);
  tbl[2 * i + 1] = sinf(a);
}

// ---------------- QKV GEMM: m97 structure + fused RoPE epilogue ----------------
// qkv[row][col] = x[row][:] . Wqkv[col][:] + bias. BM=BN=128, BK=64, 4 waves (2x2).
// Column block bn maps to one section/head: bn<16 -> Q head bn; bn<32 -> K head bn-16;
// bn>=32 -> V head bn-32 (plain f16 write to qkvb v-section; k_vtrans transposes later).
// Q/K epilogue applies RoPE in-register: pair (2d,2d+1) = adjacent cols = lane^1 ->
// __shfl_xor(v,1); cos/sin from tbl (L2-resident). Q additionally scaled by
// (1/sqrt(128))*log2(e) so attention uses exp2 directly.
// Latency hiding via cross-block co-residency (R9: 35% MfmaUtil, 0 conflicts).
// Swizzle (R4-measured 0 conflicts): linear LDS dest + pre-swizzled global source chunk
// (lane&7)^(lane>>3); read chunk = logical ^ (colq&7).
__global__ __launch_bounds__(256) void k_gemm_qkv(const f16* __restrict__ A,
                                                  const f16* __restrict__ Bt,
                                                  const float* __restrict__ bias,
                                                  const float* __restrict__ tbl,
                                                  f16* __restrict__ Qb,
                                                  f16* __restrict__ Kb,
                                                  f16* __restrict__ qkvb,
                                                  int K) {
  __shared__ f16 sA[128 * 64];
  __shared__ f16 sB[128 * 64];
  const int tid = threadIdx.x;
  const int w = tid >> 6, lane = tid & 63;
  const int g = lane >> 4, colq = lane & 15;
  const int wr = w >> 1, wc = w & 1;

  // bijective XCD swizzle (1536 % 8 == 0), bm-fast within XCD chunk
  const int nwg = gridDim.x;
  const int q8 = nwg >> 3;
  const int swz = (blockIdx.x & 7) * q8 + (blockIdx.x >> 3);
  const int bm = swz & 31, bn = swz >> 5;  // gy = 32

  const f16* Ab = A + (size_t)bm * 128 * K;
  const f16* Bb = Bt + (size_t)bn * 128 * K;
  const int nt = K >> 6;

  const int srow = lane >> 3;               // 0..7
  const int schunk = (lane & 7) ^ srow;     // pre-swizzled source chunk
  const int cq7 = colq & 7;

  f4 acc[4][4] = {};
  const int rowA0 = wr * 64 + colq;
  const int rowB0 = wc * 64 + colq;

  for (int t = 0; t < nt; ++t) {
    const int k0 = t << 6;
#pragma unroll
    for (int j = 0; j < 4; ++j) {
      const int r = (w * 4 + j) * 8;
      gl_lds16(Ab + (size_t)(r + srow) * K + k0 + schunk * 8, sA + r * 64);
      gl_lds16(Bb + (size_t)(r + srow) * K + k0 + schunk * 8, sB + r * 64);
    }
    __syncthreads();
    h8 af[2][4], bf[2][4];
#pragma unroll
    for (int kki = 0; kki < 2; ++kki) {
#pragma unroll
      for (int m = 0; m < 4; ++m)
        af[kki][m] = *(const h8*)(sA + (rowA0 + m * 16) * 64 + (((kki * 4 + g) ^ cq7) * 8));
#pragma unroll
      for (int n = 0; n < 4; ++n)
        bf[kki][n] = *(const h8*)(sB + (rowB0 + n * 16) * 64 + (((kki * 4 + g) ^ cq7) * 8));
    }
#pragma unroll
    for (int m = 0; m < 4; ++m)
#pragma unroll
      for (int n = 0; n < 4; ++n)
#pragma unroll
        for (int kki = 0; kki < 2; ++kki)
          acc[m][n] = mfma16(af[kki][m], bf[kki][n], acc[m][n]);
    __syncthreads();
  }

  // ---- epilogue ----
  const int sect = bn >> 4;    // 0=q 1=k 2=v
  const int h = bn & 15;
  if (sect == 2) {
    // plain f16 write into qkvb v-section (cols 4096..6143)
#pragma unroll
    for (int n = 0; n < 4; ++n) {
      const int col = bn * 128 + wc * 64 + n * 16 + colq;
      const float bv = bias[col];
#pragma unroll
      for (int m = 0; m < 4; ++m) {
        const int row0 = bm * 128 + wr * 64 + m * 16 + 4 * g;
#pragma unroll
        for (int r = 0; r < 4; ++r)
          qkvb[(size_t)(row0 + r) * 6144 + col] = (f16)(acc[m][n][r] + bv);
      }
    }
  } else {
    f16* Out = sect ? Kb : Qb;
    const float SQ = 0.088388347648318447f * 1.4426950408889634f;
    const float scale = sect ? 1.0f : SQ;
    const float2* tbl2 = (const float2*)tbl;
#pragma unroll
    for (int n = 0; n < 4; ++n) {
      const int col = bn * 128 + wc * 64 + n * 16 + colq;
      const int d = col & 127;
      const int dd = d >> 1;
      const bool odd = (d & 1) != 0;
      const float bv = bias[col];
#pragma unroll
      for (int m = 0; m < 4; ++m) {
        const int row0 = bm * 128 + wr * 64 + m * 16 + 4 * g;
#pragma unroll
        for (int r = 0; r < 4; ++r) {
          const int row = row0 + r;
          const int t = row & 2047;
          const int b = row >> 11;
          float v = acc[m][n][r] + bv;
          float p = __shfl_xor(v, 1);
          float2 cs = tbl2[t * 64 + dd];
          float o = odd ? (v * cs.x + p * cs.y) : (v * cs.x - p * cs.y);
          Out[((size_t)(b * 16 + h) * 2048 + t) * 128 + d] = (f16)(o * scale);
        }
      }
    }
  }
}

// ---------------- GEMM B: 128x256 tile, depth-2 counted vmcnt (out-proj; R4/R8 measured) ----------------
template <int F32OUT>
__global__ __launch_bounds__(512, 2) void k_gemm128(const f16* __restrict__ A,
                                                    const f16* __restrict__ Bt,
                                                    const float* __restrict__ bias,
                                                    void* __restrict__ Cp,
                                                    int M, int N, int K, int gy) {
  __shared__ f16 lds[2][24576];  // per buf: A[128][64] then B[256][64]
  const int tid = threadIdx.x;
  const int w = tid >> 6, lane = tid & 63;
  const int g = lane >> 4, colq = lane & 15;
  const int wr = w >> 2, wc = w & 3;

  const int nwg = gridDim.x;
  const int q8 = nwg >> 3;
  const int swz = (blockIdx.x & 7) * q8 + (blockIdx.x >> 3);
  const int bm = swz % gy, bn = swz / gy;

  const f16* Ab = A + (size_t)bm * 128 * K;
  const f16* Bb = Bt + (size_t)bn * 256 * K;

  const int srow = lane >> 3;               // 0..7
  const int schunk = (lane & 7) ^ srow;     // pre-swizzled source chunk
  const int nt = K >> 6;

  auto STAGE = [&](int kt, f16* buf) {
    const int k0 = kt << 6;
    f16* bA = buf;
    f16* bB = buf + 128 * 64;
#pragma unroll
    for (int j = 0; j < 2; ++j) {
      const int r = w * 16 + j * 8;  // + srow per lane
      gl_lds16(Ab + (size_t)(r + srow) * K + k0 + schunk * 8, bA + r * 64);
    }
#pragma unroll
    for (int j = 0; j < 4; ++j) {
      const int r = w * 32 + j * 8;
      gl_lds16(Bb + (size_t)(r + srow) * K + k0 + schunk * 8, bB + r * 64);
    }
  };

  STAGE(0, lds[0]);
  STAGE(1, lds[1]);
  asm volatile("s_waitcnt vmcnt(6)" ::: "memory");
  __builtin_amdgcn_s_barrier();

  f4 acc[4][4] = {};
  const int rowA0 = wr * 64 + colq;
  const int rowB0 = wc * 64 + colq;
  const int cq7 = colq & 7;

  for (int t = 0; t < nt; ++t) {
    f16* cur = lds[t & 1];
    h8 af[2][4], bf[2][4];
#pragma unroll
    for (int kki = 0; kki < 2; ++kki) {
#pragma unroll
      for (int m = 0; m < 4; ++m)
        af[kki][m] = *(const h8*)(cur + (rowA0 + m * 16) * 64 + (((kki * 4 + g) ^ cq7) * 8));
#pragma unroll
      for (int n = 0; n < 4; ++n)
        bf[kki][n] = *(const h8*)(cur + 8192 + (rowB0 + n * 16) * 64 + (((kki * 4 + g) ^ cq7) * 8));
    }
    asm volatile("s_waitcnt lgkmcnt(0)" ::: "memory");
    __builtin_amdgcn_s_barrier();  // all waves done reading cur
    const bool more = (t + 2 < nt);
    if (more) STAGE(t + 2, cur);
    __builtin_amdgcn_s_setprio(1);
#pragma unroll
    for (int m = 0; m < 4; ++m)
#pragma unroll
      for (int n = 0; n < 4; ++n)
#pragma unroll
        for (int kki = 0; kki < 2; ++kki)
          acc[m][n] = mfma16(af[kki][m], bf[kki][n], acc[m][n]);
    __builtin_amdgcn_s_setprio(0);
    if (more) {
      asm volatile("s_waitcnt vmcnt(6)" ::: "memory");
    } else {
      asm volatile("s_waitcnt vmcnt(0)" ::: "memory");
    }
    __builtin_amdgcn_s_barrier();
  }

#pragma unroll
  for (int n = 0; n < 4; ++n) {
    const int col = bn * 256 + wc * 64 + n * 16 + colq;
    const float bv = bias[col];
#pragma unroll
    for (int m = 0; m < 4; ++m) {
      const int row0 = bm * 128 + wr * 64 + m * 16 + 4 * g;
#pragma unroll
      for (int r = 0; r < 4; ++r) {
        float v = acc[m][n][r] + bv;
        if constexpr (F32OUT) {
          ((float*)Cp)[(size_t)(row0 + r) * N + col] = v;
        } else {
          ((f16*)Cp)[(size_t)(row0 + r) * N + col] = (f16)v;
        }
      }
    }
  }
}

// ---------------- V transpose: qkv v-section -> Vt[bh][d][t] ----------------
__global__ __launch_bounds__(256) void k_vtrans(const f16* __restrict__ qkv,
                                                f16* __restrict__ Vt) {
  __shared__ f16 ldsT[128 * 40];
  const int bh = blockIdx.y, t0 = blockIdx.x * 32;
  const int b = bh >> 4, h = bh & 15;
  const int tid = threadIdx.x;
#pragma unroll
  for (int cc = 0; cc < 2; ++cc) {
    int task = tid + cc * 256;
    int row = task >> 4;
    int ch = task & 15;
    h8 v = *(const h8*)(qkv + (size_t)(b * 2048 + t0 + row) * 6144 + 4096 + h * 128 + ch * 8);
#pragma unroll
    for (int j = 0; j < 8; ++j) ldsT[(ch * 8 + j) * 40 + row] = v[j];
  }
  __syncthreads();
  int d = tid >> 1, seg = tid & 1;
  h8 v0 = *(const h8*)(ldsT + d * 40 + seg * 16);
  h8 v1 = *(const h8*)(ldsT + d * 40 + seg * 16 + 8);
  f16* dst = Vt + ((size_t)bh * 128 + d) * 2048 + t0 + seg * 16;
  *(h8*)dst = v0;
  *(h8*)(dst + 8) = v1;
}

// ---------------- causal flash attention, LDS-staged, 2 blocks/CU ----------------
// Grid 512 (= 2/CU): one 128-row panel per block. Fold map: bids c and c+256 carry
// panels p and 15-p of the SAME head (bid&31) -> co-resident pair sums to constant
// work (36 iters/CU) and shares KV in L2. Cross-block co-residency hides the
// per-iteration vmcnt(0) drain (R9 mechanism).
DEVI void stage_tiles(const f16* __restrict__ Kg, const f16* __restrict__ Vtg,
                      f16* bufK, f16* bufV, int kv, int w, int lane) {
#pragma unroll
  for (int jj = 0; jj < 4; ++jj) {
    const int j = w * 4 + jj;
    const int rK = j * 4 + (lane >> 4);
    const int cK = (lane & 15) ^ ((rK & 7) << 1);
    gl_lds16(Kg + (size_t)(kv + rK) * 128 + cK * 8, bufK + j * 512);
    const int rV = j * 8 + (lane >> 3);
    const int cV = (lane & 7) ^ (rV & 7);
    gl_lds16(Vtg + (size_t)rV * 2048 + kv + cV * 8, bufV + j * 512);
  }
}

__global__ __launch_bounds__(256) void k_attn(const f16* __restrict__ Q,
                                              const f16* __restrict__ K,
                                              const f16* __restrict__ Vt,
                                              f16* __restrict__ O) {
  __shared__ f16 lds[2][16384];  // per buffer: K tile [0,8192), V tile [8192,16384)
  const int tid = threadIdx.x;
  const int w = tid >> 6, lane = tid & 63;
  const int g = lane >> 4, q = lane & 15;
  const int bid = blockIdx.x;
  const int bh = bid & 31;
  const int p = (bid < 256) ? (bid >> 5) : (15 - ((bid - 256) >> 5));  // panel 0..15

  const f16* Kg = K + (size_t)bh * 2048 * 128;
  const f16* Vtg = Vt + (size_t)bh * 128 * 2048;
  const int qx2 = (q & 7) << 1;
  const int qx = q & 7;

  const int q0w = p * 128 + w * 32;
  const int nit = 2 * (p + 1);

  h8 qf[2][4];
#pragma unroll
  for (int set = 0; set < 2; ++set)
#pragma unroll
    for (int d4 = 0; d4 < 4; ++d4)
      qf[set][d4] = *(const h8*)(Q + ((size_t)bh * 2048 + q0w + 16 * set + q) * 128 + d4 * 32 + g * 8);

  stage_tiles(Kg, Vtg, lds[0], lds[0] + 8192, 0, w, lane);
  asm volatile("s_waitcnt vmcnt(0)" ::: "memory");
  __builtin_amdgcn_s_barrier();

  f4 ot[2][8] = {};
  float mrun[2] = {-3.0e38f, -3.0e38f};
  float lrun[2] = {0.f, 0.f};

  for (int it = 0; it < nit; ++it) {
    const int kv0 = it * 64;
    f16* bufK = lds[it & 1];
    f16* bufV = bufK + 8192;
    if (it + 1 < nit) {
      f16* nb = lds[(it + 1) & 1];
      stage_tiles(Kg, Vtg, nb, nb + 8192, kv0 + 64, w, lane);
    }
    if (kv0 < q0w + 32) {
      f4 st[2][4] = {{{0.f,0.f,0.f,0.f},{0.f,0.f,0.f,0.f},{0.f,0.f,0.f,0.f},{0.f,0.f,0.f,0.f}},
                     {{0.f,0.f,0.f,0.f},{0.f,0.f,0.f,0.f},{0.f,0.f,0.f,0.f},{0.f,0.f,0.f,0.f}}};
#pragma unroll
      for (int d4 = 0; d4 < 4; ++d4) {
        h8 kf[4];
#pragma unroll
        for (int s = 0; s < 4; ++s)
          kf[s] = *(const h8*)(bufK + ((16 * s + q) * 16 + ((4 * d4 + g) ^ qx2)) * 8);
#pragma unroll
        for (int set = 0; set < 2; ++set)
#pragma unroll
          for (int s = 0; s < 4; ++s)
            st[set][s] = mfma16(kf[s], qf[set][d4], st[set][s]);
      }
      if (kv0 + 63 > q0w) {
#pragma unroll
        for (int set = 0; set < 2; ++set) {
          const int qcol = q0w + 16 * set + q;
#pragma unroll
          for (int s = 0; s < 4; ++s)
#pragma unroll
            for (int r = 0; r < 4; ++r)
              if (kv0 + s * 16 + 4 * g + r > qcol) st[set][s][r] = -3.0e38f;
        }
      }
      float pm[2];
#pragma unroll
      for (int set = 0; set < 2; ++set) {
        float m0 = st[set][0][0];
#pragma unroll
        for (int s = 0; s < 4; ++s)
#pragma unroll
          for (int r = 0; r < 4; ++r) m0 = fmaxf(m0, st[set][s][r]);
        m0 = fmaxf(m0, __shfl_xor(m0, 16));
        m0 = fmaxf(m0, __shfl_xor(m0, 32));
        pm[set] = m0;
      }
      const bool ok = (pm[0] <= mrun[0] + 8.0f) && (pm[1] <= mrun[1] + 8.0f);
      if (!__all(ok)) {
#pragma unroll
        for (int set = 0; set < 2; ++set) {
          float mnew = fmaxf(mrun[set], pm[set]);
          float corr = exp2f(mrun[set] - mnew);
          lrun[set] *= corr;
#pragma unroll
          for (int dt = 0; dt < 8; ++dt) ot[set][dt] *= corr;
          mrun[set] = mnew;
        }
      }
#pragma unroll
      for (int set = 0; set < 2; ++set) {
        float ps = 0.f;
#pragma unroll
        for (int s = 0; s < 4; ++s)
#pragma unroll
          for (int r = 0; r < 4; ++r) {
            st[set][s][r] = exp2f(st[set][s][r] - mrun[set]);
            ps += st[set][s][r];
          }
        ps += __shfl_xor(ps, 16);
        ps += __shfl_xor(ps, 32);
        lrun[set] += ps;
      }
      union { u32 u[4]; h8 h; } pb[2][2];
      const int s0l = ((g & 1) << 5) | q;
      const bool hi = g >= 2;
#pragma unroll
      for (int set = 0; set < 2; ++set)
#pragma unroll
        for (int hh = 0; hh < 2; ++hh) {
          u32 wA0 = pkh2(st[set][2 * hh][0], st[set][2 * hh][1]);
          u32 wB0 = pkh2(st[set][2 * hh][2], st[set][2 * hh][3]);
          u32 wA1 = pkh2(st[set][2 * hh + 1][0], st[set][2 * hh + 1][1]);
          u32 wB1 = pkh2(st[set][2 * hh + 1][2], st[set][2 * hh + 1][3]);
          u32 a0 = (u32)__shfl((int)wA0, s0l),      a1 = (u32)__shfl((int)wA1, s0l);
          u32 b0 = (u32)__shfl((int)wB0, s0l),      b1 = (u32)__shfl((int)wB1, s0l);
          u32 c0 = (u32)__shfl((int)wA0, s0l + 16), c1 = (u32)__shfl((int)wA1, s0l + 16);
          u32 d0 = (u32)__shfl((int)wB0, s0l + 16), d1 = (u32)__shfl((int)wB1, s0l + 16);
          pb[set][hh].u[0] = hi ? a1 : a0;
          pb[set][hh].u[1] = hi ? b1 : b0;
          pb[set][hh].u[2] = hi ? c1 : c0;
          pb[set][hh].u[3] = hi ? d1 : d0;
        }
#pragma unroll
      for (int hh = 0; hh < 2; ++hh)
#pragma unroll
        for (int dt = 0; dt < 8; ++dt) {
          h8 vf = *(const h8*)(bufV + ((dt * 16 + q) * 8 + ((4 * hh + g) ^ qx)) * 8);
#pragma unroll
          for (int set = 0; set < 2; ++set)
            ot[set][dt] = mfma16(vf, pb[set][hh].h, ot[set][dt]);
        }
    }
    asm volatile("s_waitcnt vmcnt(0)" ::: "memory");
    __builtin_amdgcn_s_barrier();
  }

#pragma unroll
  for (int set = 0; set < 2; ++set) {
    float linv = 1.0f / lrun[set];
    f16* Ob = O + ((size_t)(bh >> 4) * 2048 + q0w + 16 * set + q) * 2048 + (bh & 15) * 128 + 4 * g;
#pragma unroll
    for (int dt = 0; dt < 8; ++dt) {
      union { f16 hh4[4]; u64 u; } o;
#pragma unroll
      for (int r = 0; r < 4; ++r) o.hh4[r] = (f16)(ot[set][dt][r] * linv);
      *(u64*)(Ob + dt * 16) = o.u;
    }
  }
}

// ---------------- launch ----------------
extern "C" void kernel_launch(void* const* d_in, const int* in_sizes, int n_in,
                              void* d_out, int out_size, void* d_ws, size_t ws_size,
                              hipStream_t stream) {
  (void)in_sizes; (void)n_in; (void)out_size; (void)ws_size;
  const float* x    = (const float*)d_in[0];
  const float* Wqkv = (const float*)d_in[1];
  const float* bqkv = (const float*)d_in[2];
  const float* Wo   = (const float*)d_in[3];
  const float* bo   = (const float*)d_in[4];

  char* ws = (char*)d_ws;
  f16* xb    = (f16*)ws; ws += (size_t)4096 * 2048 * 2;
  f16* wqkvb = (f16*)ws; ws += (size_t)6144 * 2048 * 2;
  f16* wob   = (f16*)ws; ws += (size_t)2048 * 2048 * 2;
  f16* qkvb  = (f16*)ws; ws += (size_t)4096 * 6144 * 2;
  f16* Qb    = (f16*)ws; ws += (size_t)32 * 2048 * 128 * 2;
  f16* Kb    = (f16*)ws; ws += (size_t)32 * 2048 * 128 * 2;
  f16* Vtb   = (f16*)ws; ws += (size_t)32 * 128 * 2048 * 2;
  f16* attb  = (f16*)ws; ws += (size_t)4096 * 2048 * 2;
  float* tbl = (float*)ws; ws += (size_t)2048 * 64 * 2 * 4;

  k_cvt<<<8192, 256, 0, stream>>>(x, xb, 2097152);
  k_cvt<<<12288, 256, 0, stream>>>(Wqkv, wqkvb, 3145728);
  k_cvt<<<4096, 256, 0, stream>>>(Wo, wob, 1048576);
  k_rope_tbl<<<512, 256, 0, stream>>>(tbl);

  // QKV with fused RoPE epilogue: 1536 blocks (6/CU, balanced)
  k_gemm_qkv<<<1536, 256, 0, stream>>>(xb, wqkvb, bqkv, tbl, Qb, Kb, qkvb, 2048);

  // V transpose (reads qkvb v-section only)
  k_vtrans<<<dim3(64, 32), 256, 0, stream>>>(qkvb, Vtb);

  // attention: 512 blocks = 2/CU, fold-paired panels
  k_attn<<<512, 256, 0, stream>>>(Qb, Kb, Vtb, attb);

  // out-proj: 128x256 tiles, 256 blocks (1 exact round) — R8 proven
  k_gemm128<1><<<256, 512, 0, stream>>>(attb, wob, bo, d_out, 4096, 2048, 2048, 32);
}

// Round 11
// 312.914 us; speedup vs baseline: 1.0406x; 1.0027x over previous
//
#include <hip/hip_runtime.h>

using f16 = _Float16;
typedef _Float16 h8 __attribute__((ext_vector_type(8)));
typedef _Float16 h4 __attribute__((ext_vector_type(4)));
typedef float f4 __attribute__((ext_vector_type(4)));
typedef unsigned int u32;
typedef unsigned long long u64;

#define DEVI static __device__ __forceinline__

DEVI f4 mfma16(h8 a, h8 b, f4 c) {
  return __builtin_amdgcn_mfma_f32_16x16x32_f16(a, b, c, 0, 0, 0);
}

// async global->LDS, 16B per lane. lds base must be wave-uniform; HW scatters lane i at base + i*16.
DEVI void gl_lds16(const f16* g, f16* l) {
  __builtin_amdgcn_global_load_lds(
      (const __attribute__((address_space(1))) u32*)g,
      (__attribute__((address_space(3))) u32*)l, 16, 0, 0);
}

DEVI u32 pkh2(float a, float b) {
  union { f16 h[2]; u32 u; } x;
  x.h[0] = (f16)a; x.h[1] = (f16)b;
  return x.u;
}

// ---------------- fp32 -> fp16 convert ----------------
typedef float fv4 __attribute__((ext_vector_type(4)));

__global__ __launch_bounds__(256) void k_cvt(const float* __restrict__ in,
                                             f16* __restrict__ out, int n4) {
  int i = blockIdx.x * 256 + threadIdx.x;
  if (i >= n4) return;
  fv4 v = ((const fv4*)in)[i];
  h4 o;
  o[0] = (f16)v[0]; o[1] = (f16)v[1]; o[2] = (f16)v[2]; o[3] = (f16)v[3];
  ((h4*)out)[i] = o;
}

// ---------------- RoPE cos/sin table ----------------
__global__ __launch_bounds__(256) void k_rope_tbl(float* __restrict__ tbl) {
  int i = blockIdx.x * 256 + threadIdx.x;  // 2048*64
  int t = i >> 6, d = i & 63;
  float invf = exp2f(-(float)d * (13.287712379549449f / 64.f));
  float a = (float)t * invf;
  tbl[2 * i]     = cosf(a);
  tbl[2 * i + 1] = sinf(a);
}

// ---------------- QKV GEMM: m97 structure + fused RoPE epilogue ----------------
// R11 change: __launch_bounds__(256, 6) pins 6 waves/EU = 6 blocks/CU (R9's occupancy).
// R10's rope epilogue raised VGPR 84->100, cutting co-residency 6->5 blocks/CU and
// taxing the whole main loop (MfmaUtil 35->30). Cap restores it; any register pressure
// lands on the one-time epilogue (amortized over 32 K-tiles).
__global__ __launch_bounds__(256, 6) void k_gemm_qkv(const f16* __restrict__ A,
                                                     const f16* __restrict__ Bt,
                                                     const float* __restrict__ bias,
                                                     const float* __restrict__ tbl,
                                                     f16* __restrict__ Qb,
                                                     f16* __restrict__ Kb,
                                                     f16* __restrict__ qkvb,
                                                     int K) {
  __shared__ f16 sA[128 * 64];
  __shared__ f16 sB[128 * 64];
  const int tid = threadIdx.x;
  const int w = tid >> 6, lane = tid & 63;
  const int g = lane >> 4, colq = lane & 15;
  const int wr = w >> 1, wc = w & 1;

  // bijective XCD swizzle (1536 % 8 == 0), bm-fast within XCD chunk
  const int nwg = gridDim.x;
  const int q8 = nwg >> 3;
  const int swz = (blockIdx.x & 7) * q8 + (blockIdx.x >> 3);
  const int bm = swz & 31, bn = swz >> 5;  // gy = 32

  const f16* Ab = A + (size_t)bm * 128 * K;
  const f16* Bb = Bt + (size_t)bn * 128 * K;
  const int nt = K >> 6;

  const int srow = lane >> 3;               // 0..7
  const int schunk = (lane & 7) ^ srow;     // pre-swizzled source chunk
  const int cq7 = colq & 7;

  f4 acc[4][4] = {};
  const int rowA0 = wr * 64 + colq;
  const int rowB0 = wc * 64 + colq;

  for (int t = 0; t < nt; ++t) {
    const int k0 = t << 6;
#pragma unroll
    for (int j = 0; j < 4; ++j) {
      const int r = (w * 4 + j) * 8;
      gl_lds16(Ab + (size_t)(r + srow) * K + k0 + schunk * 8, sA + r * 64);
      gl_lds16(Bb + (size_t)(r + srow) * K + k0 + schunk * 8, sB + r * 64);
    }
    __syncthreads();
    h8 af[2][4], bf[2][4];
#pragma unroll
    for (int kki = 0; kki < 2; ++kki) {
#pragma unroll
      for (int m = 0; m < 4; ++m)
        af[kki][m] = *(const h8*)(sA + (rowA0 + m * 16) * 64 + (((kki * 4 + g) ^ cq7) * 8));
#pragma unroll
      for (int n = 0; n < 4; ++n)
        bf[kki][n] = *(const h8*)(sB + (rowB0 + n * 16) * 64 + (((kki * 4 + g) ^ cq7) * 8));
    }
#pragma unroll
    for (int m = 0; m < 4; ++m)
#pragma unroll
      for (int n = 0; n < 4; ++n)
#pragma unroll
        for (int kki = 0; kki < 2; ++kki)
          acc[m][n] = mfma16(af[kki][m], bf[kki][n], acc[m][n]);
    __syncthreads();
  }

  // ---- epilogue ----
  const int sect = bn >> 4;    // 0=q 1=k 2=v
  const int h = bn & 15;
  if (sect == 2) {
    // plain f16 write into qkvb v-section (cols 4096..6143)
#pragma unroll
    for (int n = 0; n < 4; ++n) {
      const int col = bn * 128 + wc * 64 + n * 16 + colq;
      const float bv = bias[col];
#pragma unroll
      for (int m = 0; m < 4; ++m) {
        const int row0 = bm * 128 + wr * 64 + m * 16 + 4 * g;
#pragma unroll
        for (int r = 0; r < 4; ++r)
          qkvb[(size_t)(row0 + r) * 6144 + col] = (f16)(acc[m][n][r] + bv);
      }
    }
  } else {
    f16* Out = sect ? Kb : Qb;
    const float SQ = 0.088388347648318447f * 1.4426950408889634f;
    const float scale = sect ? 1.0f : SQ;
    const float2* tbl2 = (const float2*)tbl;
#pragma unroll
    for (int n = 0; n < 4; ++n) {
      const int col = bn * 128 + wc * 64 + n * 16 + colq;
      const int d = col & 127;
      const int dd = d >> 1;
      const bool odd = (d & 1) != 0;
      const float bv = bias[col];
#pragma unroll
      for (int m = 0; m < 4; ++m) {
        const int row0 = bm * 128 + wr * 64 + m * 16 + 4 * g;
#pragma unroll
        for (int r = 0; r < 4; ++r) {
          const int row = row0 + r;
          const int t = row & 2047;
          const int b = row >> 11;
          float v = acc[m][n][r] + bv;
          float p = __shfl_xor(v, 1);
          float2 cs = tbl2[t * 64 + dd];
          float o = odd ? (v * cs.x + p * cs.y) : (v * cs.x - p * cs.y);
          Out[((size_t)(b * 16 + h) * 2048 + t) * 128 + d] = (f16)(o * scale);
        }
      }
    }
  }
}

// ---------------- GEMM B: 128x256 tile, depth-2 counted vmcnt (out-proj; R4/R8 measured) ----------------
template <int F32OUT>
__global__ __launch_bounds__(512, 2) void k_gemm128(const f16* __restrict__ A,
                                                    const f16* __restrict__ Bt,
                                                    const float* __restrict__ bias,
                                                    void* __restrict__ Cp,
                                                    int M, int N, int K, int gy) {
  __shared__ f16 lds[2][24576];  // per buf: A[128][64] then B[256][64]
  const int tid = threadIdx.x;
  const int w = tid >> 6, lane = tid & 63;
  const int g = lane >> 4, colq = lane & 15;
  const int wr = w >> 2, wc = w & 3;

  const int nwg = gridDim.x;
  const int q8 = nwg >> 3;
  const int swz = (blockIdx.x & 7) * q8 + (blockIdx.x >> 3);
  const int bm = swz % gy, bn = swz / gy;

  const f16* Ab = A + (size_t)bm * 128 * K;
  const f16* Bb = Bt + (size_t)bn * 256 * K;

  const int srow = lane >> 3;               // 0..7
  const int schunk = (lane & 7) ^ srow;     // pre-swizzled source chunk
  const int nt = K >> 6;

  auto STAGE = [&](int kt, f16* buf) {
    const int k0 = kt << 6;
    f16* bA = buf;
    f16* bB = buf + 128 * 64;
#pragma unroll
    for (int j = 0; j < 2; ++j) {
      const int r = w * 16 + j * 8;  // + srow per lane
      gl_lds16(Ab + (size_t)(r + srow) * K + k0 + schunk * 8, bA + r * 64);
    }
#pragma unroll
    for (int j = 0; j < 4; ++j) {
      const int r = w * 32 + j * 8;
      gl_lds16(Bb + (size_t)(r + srow) * K + k0 + schunk * 8, bB + r * 64);
    }
  };

  STAGE(0, lds[0]);
  STAGE(1, lds[1]);
  asm volatile("s_waitcnt vmcnt(6)" ::: "memory");
  __builtin_amdgcn_s_barrier();

  f4 acc[4][4] = {};
  const int rowA0 = wr * 64 + colq;
  const int rowB0 = wc * 64 + colq;
  const int cq7 = colq & 7;

  for (int t = 0; t < nt; ++t) {
    f16* cur = lds[t & 1];
    h8 af[2][4], bf[2][4];
#pragma unroll
    for (int kki = 0; kki < 2; ++kki) {
#pragma unroll
      for (int m = 0; m < 4; ++m)
        af[kki][m] = *(const h8*)(cur + (rowA0 + m * 16) * 64 + (((kki * 4 + g) ^ cq7) * 8));
#pragma unroll
      for (int n = 0; n < 4; ++n)
        bf[kki][n] = *(const h8*)(cur + 8192 + (rowB0 + n * 16) * 64 + (((kki * 4 + g) ^ cq7) * 8));
    }
    asm volatile("s_waitcnt lgkmcnt(0)" ::: "memory");
    __builtin_amdgcn_s_barrier();  // all waves done reading cur
    const bool more = (t + 2 < nt);
    if (more) STAGE(t + 2, cur);
    __builtin_amdgcn_s_setprio(1);
#pragma unroll
    for (int m = 0; m < 4; ++m)
#pragma unroll
      for (int n = 0; n < 4; ++n)
#pragma unroll
        for (int kki = 0; kki < 2; ++kki)
          acc[m][n] = mfma16(af[kki][m], bf[kki][n], acc[m][n]);
    __builtin_amdgcn_s_setprio(0);
    if (more) {
      asm volatile("s_waitcnt vmcnt(6)" ::: "memory");
    } else {
      asm volatile("s_waitcnt vmcnt(0)" ::: "memory");
    }
    __builtin_amdgcn_s_barrier();
  }

#pragma unroll
  for (int n = 0; n < 4; ++n) {
    const int col = bn * 256 + wc * 64 + n * 16 + colq;
    const float bv = bias[col];
#pragma unroll
    for (int m = 0; m < 4; ++m) {
      const int row0 = bm * 128 + wr * 64 + m * 16 + 4 * g;
#pragma unroll
      for (int r = 0; r < 4; ++r) {
        float v = acc[m][n][r] + bv;
        if constexpr (F32OUT) {
          ((float*)Cp)[(size_t)(row0 + r) * N + col] = v;
        } else {
          ((f16*)Cp)[(size_t)(row0 + r) * N + col] = (f16)v;
        }
      }
    }
  }
}

// ---------------- V transpose: qkv v-section -> Vt[bh][d][t] ----------------
__global__ __launch_bounds__(256) void k_vtrans(const f16* __restrict__ qkv,
                                                f16* __restrict__ Vt) {
  __shared__ f16 ldsT[128 * 40];
  const int bh = blockIdx.y, t0 = blockIdx.x * 32;
  const int b = bh >> 4, h = bh & 15;
  const int tid = threadIdx.x;
#pragma unroll
  for (int cc = 0; cc < 2; ++cc) {
    int task = tid + cc * 256;
    int row = task >> 4;
    int ch = task & 15;
    h8 v = *(const h8*)(qkv + (size_t)(b * 2048 + t0 + row) * 6144 + 4096 + h * 128 + ch * 8);
#pragma unroll
    for (int j = 0; j < 8; ++j) ldsT[(ch * 8 + j) * 40 + row] = v[j];
  }
  __syncthreads();
  int d = tid >> 1, seg = tid & 1;
  h8 v0 = *(const h8*)(ldsT + d * 40 + seg * 16);
  h8 v1 = *(const h8*)(ldsT + d * 40 + seg * 16 + 8);
  f16* dst = Vt + ((size_t)bh * 128 + d) * 2048 + t0 + seg * 16;
  *(h8*)dst = v0;
  *(h8*)(dst + 8) = v1;
}

// ---------------- causal flash attention, LDS-staged, 2 blocks/CU ----------------
DEVI void stage_tiles(const f16* __restrict__ Kg, const f16* __restrict__ Vtg,
                      f16* bufK, f16* bufV, int kv, int w, int lane) {
#pragma unroll
  for (int jj = 0; jj < 4; ++jj) {
    const int j = w * 4 + jj;
    const int rK = j * 4 + (lane >> 4);
    const int cK = (lane & 15) ^ ((rK & 7) << 1);
    gl_lds16(Kg + (size_t)(kv + rK) * 128 + cK * 8, bufK + j * 512);
    const int rV = j * 8 + (lane >> 3);
    const int cV = (lane & 7) ^ (rV & 7);
    gl_lds16(Vtg + (size_t)rV * 2048 + kv + cV * 8, bufV + j * 512);
  }
}

__global__ __launch_bounds__(256) void k_attn(const f16* __restrict__ Q,
                                              const f16* __restrict__ K,
                                              const f16* __restrict__ Vt,
                                              f16* __restrict__ O) {
  __shared__ f16 lds[2][16384];  // per buffer: K tile [0,8192), V tile [8192,16384)
  const int tid = threadIdx.x;
  const int w = tid >> 6, lane = tid & 63;
  const int g = lane >> 4, q = lane & 15;
  const int bid = blockIdx.x;
  const int bh = bid & 31;
  const int p = (bid < 256) ? (bid >> 5) : (15 - ((bid - 256) >> 5));  // panel 0..15

  const f16* Kg = K + (size_t)bh * 2048 * 128;
  const f16* Vtg = Vt + (size_t)bh * 128 * 2048;
  const int qx2 = (q & 7) << 1;
  const int qx = q & 7;

  const int q0w = p * 128 + w * 32;
  const int nit = 2 * (p + 1);

  h8 qf[2][4];
#pragma unroll
  for (int set = 0; set < 2; ++set)
#pragma unroll
    for (int d4 = 0; d4 < 4; ++d4)
      qf[set][d4] = *(const h8*)(Q + ((size_t)bh * 2048 + q0w + 16 * set + q) * 128 + d4 * 32 + g * 8);

  stage_tiles(Kg, Vtg, lds[0], lds[0] + 8192, 0, w, lane);
  asm volatile("s_waitcnt vmcnt(0)" ::: "memory");
  __builtin_amdgcn_s_barrier();

  f4 ot[2][8] = {};
  float mrun[2] = {-3.0e38f, -3.0e38f};
  float lrun[2] = {0.f, 0.f};

  for (int it = 0; it < nit; ++it) {
    const int kv0 = it * 64;
    f16* bufK = lds[it & 1];
    f16* bufV = bufK + 8192;
    if (it + 1 < nit) {
      f16* nb = lds[(it + 1) & 1];
      stage_tiles(Kg, Vtg, nb, nb + 8192, kv0 + 64, w, lane);
    }
    if (kv0 < q0w + 32) {
      f4 st[2][4] = {{{0.f,0.f,0.f,0.f},{0.f,0.f,0.f,0.f},{0.f,0.f,0.f,0.f},{0.f,0.f,0.f,0.f}},
                     {{0.f,0.f,0.f,0.f},{0.f,0.f,0.f,0.f},{0.f,0.f,0.f,0.f},{0.f,0.f,0.f,0.f}}};
#pragma unroll
      for (int d4 = 0; d4 < 4; ++d4) {
        h8 kf[4];
#pragma unroll
        for (int s = 0; s < 4; ++s)
          kf[s] = *(const h8*)(bufK + ((16 * s + q) * 16 + ((4 * d4 + g) ^ qx2)) * 8);
#pragma unroll
        for (int set = 0; set < 2; ++set)
#pragma unroll
          for (int s = 0; s < 4; ++s)
            st[set][s] = mfma16(kf[s], qf[set][d4], st[set][s]);
      }
      if (kv0 + 63 > q0w) {
#pragma unroll
        for (int set = 0; set < 2; ++set) {
          const int qcol = q0w + 16 * set + q;
#pragma unroll
          for (int s = 0; s < 4; ++s)
#pragma unroll
            for (int r = 0; r < 4; ++r)
              if (kv0 + s * 16 + 4 * g + r > qcol) st[set][s][r] = -3.0e38f;
        }
      }
      float pm[2];
#pragma unroll
      for (int set = 0; set < 2; ++set) {
        float m0 = st[set][0][0];
#pragma unroll
        for (int s = 0; s < 4; ++s)
#pragma unroll
          for (int r = 0; r < 4; ++r) m0 = fmaxf(m0, st[set][s][r]);
        m0 = fmaxf(m0, __shfl_xor(m0, 16));
        m0 = fmaxf(m0, __shfl_xor(m0, 32));
        pm[set] = m0;
      }
      const bool ok = (pm[0] <= mrun[0] + 8.0f) && (pm[1] <= mrun[1] + 8.0f);
      if (!__all(ok)) {
#pragma unroll
        for (int set = 0; set < 2; ++set) {
          float mnew = fmaxf(mrun[set], pm[set]);
          float corr = exp2f(mrun[set] - mnew);
          lrun[set] *= corr;
#pragma unroll
          for (int dt = 0; dt < 8; ++dt) ot[set][dt] *= corr;
          mrun[set] = mnew;
        }
      }
#pragma unroll
      for (int set = 0; set < 2; ++set) {
        float ps = 0.f;
#pragma unroll
        for (int s = 0; s < 4; ++s)
#pragma unroll
          for (int r = 0; r < 4; ++r) {
            st[set][s][r] = exp2f(st[set][s][r] - mrun[set]);
            ps += st[set][s][r];
          }
        ps += __shfl_xor(ps, 16);
        ps += __shfl_xor(ps, 32);
        lrun[set] += ps;
      }
      union { u32 u[4]; h8 h; } pb[2][2];
      const int s0l = ((g & 1) << 5) | q;
      const bool hi = g >= 2;
#pragma unroll
      for (int set = 0; set < 2; ++set)
#pragma unroll
        for (int hh = 0; hh < 2; ++hh) {
          u32 wA0 = pkh2(st[set][2 * hh][0], st[set][2 * hh][1]);
          u32 wB0 = pkh2(st[set][2 * hh][2], st[set][2 * hh][3]);
          u32 wA1 = pkh2(st[set][2 * hh + 1][0], st[set][2 * hh + 1][1]);
          u32 wB1 = pkh2(st[set][2 * hh + 1][2], st[set][2 * hh + 1][3]);
          u32 a0 = (u32)__shfl((int)wA0, s0l),      a1 = (u32)__shfl((int)wA1, s0l);
          u32 b0 = (u32)__shfl((int)wB0, s0l),      b1 = (u32)__shfl((int)wB1, s0l);
          u32 c0 = (u32)__shfl((int)wA0, s0l + 16), c1 = (u32)__shfl((int)wA1, s0l + 16);
          u32 d0 = (u32)__shfl((int)wB0, s0l + 16), d1 = (u32)__shfl((int)wB1, s0l + 16);
          pb[set][hh].u[0] = hi ? a1 : a0;
          pb[set][hh].u[1] = hi ? b1 : b0;
          pb[set][hh].u[2] = hi ? c1 : c0;
          pb[set][hh].u[3] = hi ? d1 : d0;
        }
#pragma unroll
      for (int hh = 0; hh < 2; ++hh)
#pragma unroll
        for (int dt = 0; dt < 8; ++dt) {
          h8 vf = *(const h8*)(bufV + ((dt * 16 + q) * 8 + ((4 * hh + g) ^ qx)) * 8);
#pragma unroll
          for (int set = 0; set < 2; ++set)
            ot[set][dt] = mfma16(vf, pb[set][hh].h, ot[set][dt]);
        }
    }
    asm volatile("s_waitcnt vmcnt(0)" ::: "memory");
    __builtin_amdgcn_s_barrier();
  }

#pragma unroll
  for (int set = 0; set < 2; ++set) {
    float linv = 1.0f / lrun[set];
    f16* Ob = O + ((size_t)(bh >> 4) * 2048 + q0w + 16 * set + q) * 2048 + (bh & 15) * 128 + 4 * g;
#pragma unroll
    for (int dt = 0; dt < 8; ++dt) {
      union { f16 hh4[4]; u64 u; } o;
#pragma unroll
      for (int r = 0; r < 4; ++r) o.hh4[r] = (f16)(ot[set][dt][r] * linv);
      *(u64*)(Ob + dt * 16) = o.u;
    }
  }
}

// ---------------- launch ----------------
extern "C" void kernel_launch(void* const* d_in, const int* in_sizes, int n_in,
                              void* d_out, int out_size, void* d_ws, size_t ws_size,
                              hipStream_t stream) {
  (void)in_sizes; (void)n_in; (void)out_size; (void)ws_size;
  const float* x    = (const float*)d_in[0];
  const float* Wqkv = (const float*)d_in[1];
  const float* bqkv = (const float*)d_in[2];
  const float* Wo   = (const float*)d_in[3];
  const float* bo   = (const float*)d_in[4];

  char* ws = (char*)d_ws;
  f16* xb    = (f16*)ws; ws += (size_t)4096 * 2048 * 2;
  f16* wqkvb = (f16*)ws; ws += (size_t)6144 * 2048 * 2;
  f16* wob   = (f16*)ws; ws += (size_t)2048 * 2048 * 2;
  f16* qkvb  = (f16*)ws; ws += (size_t)4096 * 6144 * 2;
  f16* Qb    = (f16*)ws; ws += (size_t)32 * 2048 * 128 * 2;
  f16* Kb    = (f16*)ws; ws += (size_t)32 * 2048 * 128 * 2;
  f16* Vtb   = (f16*)ws; ws += (size_t)32 * 128 * 2048 * 2;
  f16* attb  = (f16*)ws; ws += (size_t)4096 * 2048 * 2;
  float* tbl = (float*)ws; ws += (size_t)2048 * 64 * 2 * 4;

  k_cvt<<<8192, 256, 0, stream>>>(x, xb, 2097152);
  k_cvt<<<12288, 256, 0, stream>>>(Wqkv, wqkvb, 3145728);
  k_cvt<<<4096, 256, 0, stream>>>(Wo, wob, 1048576);
  k_rope_tbl<<<512, 256, 0, stream>>>(tbl);

  // QKV with fused RoPE epilogue: 1536 blocks (6/CU, balanced)
  k_gemm_qkv<<<1536, 256, 0, stream>>>(xb, wqkvb, bqkv, tbl, Qb, Kb, qkvb, 2048);

  // V transpose (reads qkvb v-section only)
  k_vtrans<<<dim3(64, 32), 256, 0, stream>>>(qkvb, Vtb);

  // attention: 512 blocks = 2/CU, fold-paired panels
  k_attn<<<512, 256, 0, stream>>>(Qb, Kb, Vtb, attb);

  // out-proj: 128x256 tiles, 256 blocks (1 exact round) — R8 proven
  k_gemm128<1><<<256, 512, 0, stream>>>(attb, wob, bo, d_out, 4096, 2048, 2048, 32);
}